// Round 10
// baseline (942.961 us; speedup 1.0000x reference)
//
#include <hip/hip_runtime.h>
#include <hip/hip_bf16.h>

#define BN 4096
#define DD 128

// All five bf16 matrices are pre-scaled by SQS = sqrt(2*log2(e)), so the
// MFMA dot product is directly the exp2 argument: 2^(SQS^2 * dot) = e^(2*dot).
#define SQS 1.69864356f

typedef __bf16 bf16x8 __attribute__((ext_vector_type(8)));
typedef float f32x16 __attribute__((ext_vector_type(16)));

__device__ __forceinline__ float fast_exp2(float x) {
#if __has_builtin(__builtin_amdgcn_exp2f)
    return __builtin_amdgcn_exp2f(x);
#else
    return __builtin_exp2f(x);
#endif
}

// ---------------- prep: f32 -> bf16 fragment-major (+gather), diag dots -----
// Fragment-major: per 32-row panel (8192 B), granule g = s*64 + h*32 + r
// holds row r, elements [16s+8h, 16s+8h+8).
__global__ __launch_bounds__(256) void prep_kernel(
    const float* __restrict__ z1, const float* __restrict__ z2,
    const float* __restrict__ attr, const int* __restrict__ uni,
    char* __restrict__ Z1f, char* __restrict__ Z2f,
    char* __restrict__ G1f, char* __restrict__ G2f, char* __restrict__ Af,
    float* __restrict__ d1, float* __restrict__ d2, float* __restrict__ d3,
    float* __restrict__ S1, float* __restrict__ S2, float* __restrict__ out)
{
    int p = blockIdx.x;        // half-panel 0..255 (16 rows each)
    int t = threadIdx.x;       // 0..255
    int gid = p * 256 + t;
    if (gid < 4 * BN) { S1[gid] = 0.f; S2[gid] = 0.f; }
    if (gid == 0) out[0] = 0.f;

    int r = t >> 4, q = t & 15;        // row-in-block (16), col-eighth (8 f32)
    int grow = p * 16 + r;
    int arow = uni[grow];

    __shared__ __hip_bfloat16 lp[5][16][128];

    const float* sp[5] = { z1 + (size_t)grow * DD, z2 + (size_t)grow * DD,
                           z1 + (size_t)arow * DD, z2 + (size_t)arow * DD,
                           attr + (size_t)arow * DD };
    float v[5][8];
    #pragma unroll
    for (int m = 0; m < 5; m++) {
        const float4* s4 = (const float4*)(sp[m] + q * 8);
        #pragma unroll
        for (int i = 0; i < 2; i++) {
            float4 f = s4[i];
            v[m][4*i+0] = f.x; v[m][4*i+1] = f.y;
            v[m][4*i+2] = f.z; v[m][4*i+3] = f.w;
        }
    }
    float p1 = 0.f, p2 = 0.f, p3 = 0.f;
    #pragma unroll
    for (int e = 0; e < 8; e++) {
        p3 += v[0][e] * v[1][e];
        p1 += v[2][e] * v[4][e];
        p2 += v[3][e] * v[4][e];
    }
    #pragma unroll
    for (int m = 1; m < 16; m <<= 1) {
        p1 += __shfl_xor(p1, m);
        p2 += __shfl_xor(p2, m);
        p3 += __shfl_xor(p3, m);
    }
    if (q == 0) { d1[grow] = p1; d2[grow] = p2; d3[grow] = p3; }

    #pragma unroll
    for (int m = 0; m < 5; m++)
        #pragma unroll
        for (int e = 0; e < 8; e++)
            lp[m][r][q * 8 + e] = __float2bfloat16(v[m][e] * SQS);
    __syncthreads();

    int panel = p >> 1, lo = (p & 1) * 16;
    char* dsts[5] = { Z1f, Z2f, G1f, G2f, Af };
    int s = t >> 5, h = (t >> 4) & 1, rl = t & 15;   // granule coords
    int g = s * 64 + h * 32 + lo + rl;
    #pragma unroll
    for (int m = 0; m < 5; m++) {
        bf16x8 val = *reinterpret_cast<const bf16x8*>(&lp[m][rl][s * 16 + h * 8]);
        *reinterpret_cast<bf16x8*>(dsts[m] + (size_t)panel * 8192 + (size_t)g * 16) = val;
    }
}

// ---------------- sweep: barrier-free fused sim + exp row-sum ---------------
// 3072 waves; each wave owns 64 X-rows (2 fragment-major panels in regs) and
// one 512-row Y-chunk streamed DIRECTLY into registers (no LDS, no barriers).
// Swapped MFMA operands: D = mfma(A=Y, B=X) -> D[row=Y][col=X(lane&31)], so
// the Y row-sum is the accumulation loop itself; 4 atomicAdds per lane at end.
// Wave map: gwid<1024: job 0/1 (X=G1f/G2f vs Y=Af), 64 xblk x 8 ychunk.
//           else      : job 2/3 (X=Z1f/Z2f vs Y=Z1f|Z2f), 64 xblk x 16 ychunk.
// launch_bounds(256,2): ~182 unified regs -> 2 waves/SIMD, no spill
// (WRITE_SIZE is the tripwire; r8 showed what a cap below usage does).
__global__ __launch_bounds__(256, 2) void sweep_kernel(
    const char* __restrict__ Z1f, const char* __restrict__ Z2f,
    const char* __restrict__ G1f, const char* __restrict__ G2f,
    const char* __restrict__ Af,
    float* __restrict__ S1, float* __restrict__ S2)
{
    int gwid = blockIdx.x * 4 + (threadIdx.x >> 6);
    int lane = threadIdx.x & 63;
    int r = lane & 31, h = lane >> 5;

    int job, xblk, ychunk;
    const char *X, *Y;
    if (gwid < 1024) {
        job = gwid >> 9;
        int rem = gwid & 511;
        xblk = rem >> 3;          // 0..63
        ychunk = rem & 7;         // 0..7
        X = job ? G2f : G1f;
        Y = Af;
    } else {
        int g2 = gwid - 1024;
        job = 2 + (g2 >> 10);
        int rem = g2 & 1023;
        xblk = rem >> 4;          // 0..63
        ychunk = rem & 15;        // 0..15
        X = (job == 2) ? Z1f : Z2f;
        Y = (ychunk < 8) ? Z1f : Z2f;
        ychunk &= 7;
    }

    size_t laneoff = (size_t)(h * 512 + r * 16);

    // X: two 32-row panels (B operand), held in registers for the whole sweep.
    const char* xp = X + (size_t)(xblk * 2) * 8192 + laneoff;
    bf16x8 xb0[8], xb1[8];
    #pragma unroll
    for (int s = 0; s < 8; s++) {
        xb0[s] = *reinterpret_cast<const bf16x8*>(xp + s * 1024);
        xb1[s] = *reinterpret_cast<const bf16x8*>(xp + 8192 + s * 1024);
    }

    // Y stream: 16 tiles of 32 rows (8 KB each), double-buffered in regs.
    const char* yp = Y + (size_t)ychunk * 512 * 256 + laneoff;

    float a00 = 0.f, a01 = 0.f;   // X-group 0: sum e, sum e^2
    float a10 = 0.f, a11 = 0.f;   // X-group 1

    bf16x8 yb[2][8];
    #pragma unroll
    for (int s = 0; s < 8; s++)
        yb[0][s] = *reinterpret_cast<const bf16x8*>(yp + s * 1024);

    #pragma unroll
    for (int t = 0; t < 16; t++) {
        if (t + 1 < 16) {                       // prefetch next tile to regs
            const char* ypn = yp + (size_t)(t + 1) * 8192;
            #pragma unroll
            for (int s = 0; s < 8; s++)
                yb[(t + 1) & 1][s] = *reinterpret_cast<const bf16x8*>(ypn + s * 1024);
        }
        f32x16 c0, c1;
        #pragma unroll
        for (int q = 0; q < 16; q++) { c0[q] = 0.f; c1[q] = 0.f; }
        #pragma unroll
        for (int s = 0; s < 8; s++) {
            bf16x8 yf = yb[t & 1][s];
            c0 = __builtin_amdgcn_mfma_f32_32x32x16_bf16(yf, xb0[s], c0, 0, 0, 0);
            c1 = __builtin_amdgcn_mfma_f32_32x32x16_bf16(yf, xb1[s], c1, 0, 0, 0);
        }
        // inputs pre-scaled: c = (2*log2 e)*dot -> e = e^(2*dot).
        // Row-sum over Y = accumulate the 16 regs.
        #pragma unroll
        for (int q = 0; q < 16; q++) {
            float e0 = fast_exp2(c0[q]);
            a00 += e0;
            a01 = fmaf(e0, e0, a01);
            float e1 = fast_exp2(c1[q]);
            a10 += e1;
            a11 = fmaf(e1, e1, a11);
        }
    }

    // Each lane holds partial sums (its h-half of every tile) for X-row
    // xblk*64 + xg*32 + r; both h lanes atomicAdd disjoint Y contributions.
    {
        int row0 = xblk * 64 + r;
        int row1 = xblk * 64 + 32 + r;
        atomicAdd(&S1[job * BN + row0], a00);
        atomicAdd(&S2[job * BN + row0], a01);
        atomicAdd(&S1[job * BN + row1], a10);
        atomicAdd(&S2[job * BN + row1], a11);
    }
}

// ---------------- finalize: per-row loss terms -> weighted mean --------------
__global__ __launch_bounds__(256) void finalize_kernel(
    const float* __restrict__ S1, const float* __restrict__ S2,
    const float* __restrict__ d1, const float* __restrict__ d2,
    const float* __restrict__ d3, float* __restrict__ out)
{
    int idx = blockIdx.x * 256 + threadIdx.x;   // 0..16383
    float term = 0.f;
    const float EM2 = 0.13533528323661270f;     // e^-2
    if (idx < 8192) {                           // inter jobs 0/1
        int j = idx >> 12, i = idx & 4095;
        float dv = j ? d2[i] : d1[i];
        float n = 4095.f;
        float pos = __expf(2.f * dv);
        float s1 = S1[j * BN + i] - pos;
        float s2 = S2[j * BN + i] - pos * pos;
        float rw = s2 * n / s1;
        float ng = (-0.1f * n * pos + rw) * (1.f / 0.9f);
        ng = fmaxf(ng, n * EM2);
        term = logf((pos + ng) / pos) * (0.5f / 4096.f);
    } else {                                    // intra rows 0..8191
        int i = idx - 8192;
        int ii = i & 4095;
        int job = 2 + (i >> 12);
        float n = 8190.f;
        const float E2 = 7.3890560989306495f, E4 = 54.598150033144236f;
        float pos = __expf(2.f * d3[ii]);
        float s1 = S1[job * BN + ii] - E2 - pos;
        float s2 = S2[job * BN + ii] - E4 - pos * pos;
        float rw = s2 * n / s1;
        float ng = (-0.1f * n * pos + rw) * (1.f / 0.9f);
        ng = fmaxf(ng, n * EM2);
        term = logf((pos + ng) / pos) * (1.f / 8192.f);
    }

    #pragma unroll
    for (int m = 1; m < 64; m <<= 1) term += __shfl_xor(term, m);
    __shared__ float sm[4];
    int wid = threadIdx.x >> 6;
    if ((threadIdx.x & 63) == 0) sm[wid] = term;
    __syncthreads();
    if (threadIdx.x == 0) atomicAdd(out, sm[0] + sm[1] + sm[2] + sm[3]);
}

extern "C" void kernel_launch(void* const* d_in, const int* in_sizes, int n_in,
                              void* d_out, int out_size, void* d_ws, size_t ws_size,
                              hipStream_t stream)
{
    const float* z1   = (const float*)d_in[0];
    const float* z2   = (const float*)d_in[1];
    // d_in[2] = text_z : unused by the reference
    const float* attr = (const float*)d_in[3];
    const int*   uni  = (const int*)d_in[4];
    float* out = (float*)d_out;

    char* ws = (char*)d_ws;
    size_t matb = (size_t)BN * DD * 2;               // bytes per bf16 matrix
    char* Z1f = ws;
    char* Z2f = Z1f + matb;
    char* G1f = Z2f + matb;
    char* G2f = G1f + matb;
    char* Af  = G2f + matb;
    float* S1 = (float*)(ws + 5 * matb);
    float* S2 = S1 + 4 * BN;
    float* d1 = S2 + 4 * BN;
    float* d2 = d1 + BN;
    float* d3 = d2 + BN;

    prep_kernel<<<256, 256, 0, stream>>>(z1, z2, attr, uni,
                                         Z1f, Z2f, G1f, G2f, Af,
                                         d1, d2, d3, S1, S2, out);
    sweep_kernel<<<768, 256, 0, stream>>>(Z1f, Z2f, G1f, G2f, Af, S1, S2);
    finalize_kernel<<<64, 256, 0, stream>>>(S1, S2, d1, d2, d3, out);
}

// Round 11
// 49.915 us; speedup vs baseline: 18.8912x; 18.8912x over previous
//
#include <hip/hip_runtime.h>
#include <hip/hip_bf16.h>

#define BN 4096
#define DD 128
#define NTILES 16   // 16 tiles x 32 Y-rows = 512-row chunk per block

// All five bf16 matrices are pre-scaled by SQS = sqrt(2*log2(e)), so the
// MFMA dot product is directly the exp2 argument: 2^(SQS^2 * dot) = e^(2*dot).
#define SQS 1.69864356f

typedef __bf16 bf16x8 __attribute__((ext_vector_type(8)));
typedef float f32x16 __attribute__((ext_vector_type(16)));

__device__ __forceinline__ void gload_lds16(const void* g, void* l) {
    __builtin_amdgcn_global_load_lds(
        (const __attribute__((address_space(1))) void*)g,
        (__attribute__((address_space(3))) void*)l, 16, 0, 0);
}

__device__ __forceinline__ float fast_exp2(float x) {
    return __builtin_exp2f(x);
}

// ---------------- prep: f32 -> bf16 fragment-major (+gather), diag dots -----
// Fragment-major: per 32-row panel (8192 B), granule g = s*64 + h*32 + r
// holds row r, elements [16s+8h, 16s+8h+8).
__global__ __launch_bounds__(256) void prep_kernel(
    const float* __restrict__ z1, const float* __restrict__ z2,
    const float* __restrict__ attr, const int* __restrict__ uni,
    char* __restrict__ Z1f, char* __restrict__ Z2f,
    char* __restrict__ G1f, char* __restrict__ G2f, char* __restrict__ Af,
    float* __restrict__ d1, float* __restrict__ d2, float* __restrict__ d3,
    float* __restrict__ S1, float* __restrict__ S2, float* __restrict__ out)
{
    int p = blockIdx.x;        // half-panel 0..255 (16 rows each)
    int t = threadIdx.x;       // 0..255
    int gid = p * 256 + t;
    if (gid < 4 * BN) { S1[gid] = 0.f; S2[gid] = 0.f; }
    if (gid == 0) out[0] = 0.f;

    int r = t >> 4, q = t & 15;        // row-in-block (16), col-eighth (8 f32)
    int grow = p * 16 + r;
    int arow = uni[grow];

    __shared__ __hip_bfloat16 lp[5][16][128];

    const float* sp[5] = { z1 + (size_t)grow * DD, z2 + (size_t)grow * DD,
                           z1 + (size_t)arow * DD, z2 + (size_t)arow * DD,
                           attr + (size_t)arow * DD };
    float v[5][8];
    #pragma unroll
    for (int m = 0; m < 5; m++) {
        const float4* s4 = (const float4*)(sp[m] + q * 8);
        #pragma unroll
        for (int i = 0; i < 2; i++) {
            float4 f = s4[i];
            v[m][4*i+0] = f.x; v[m][4*i+1] = f.y;
            v[m][4*i+2] = f.z; v[m][4*i+3] = f.w;
        }
    }
    float p1 = 0.f, p2 = 0.f, p3 = 0.f;
    #pragma unroll
    for (int e = 0; e < 8; e++) {
        p3 += v[0][e] * v[1][e];
        p1 += v[2][e] * v[4][e];
        p2 += v[3][e] * v[4][e];
    }
    #pragma unroll
    for (int m = 1; m < 16; m <<= 1) {
        p1 += __shfl_xor(p1, m);
        p2 += __shfl_xor(p2, m);
        p3 += __shfl_xor(p3, m);
    }
    if (q == 0) { d1[grow] = p1; d2[grow] = p2; d3[grow] = p3; }

    #pragma unroll
    for (int m = 0; m < 5; m++)
        #pragma unroll
        for (int e = 0; e < 8; e++)
            lp[m][r][q * 8 + e] = __float2bfloat16(v[m][e] * SQS);
    __syncthreads();

    int panel = p >> 1, lo = (p & 1) * 16;
    char* dsts[5] = { Z1f, Z2f, G1f, G2f, Af };
    int s = t >> 5, h = (t >> 4) & 1, rl = t & 15;   // granule coords
    int g = s * 64 + h * 32 + lo + rl;
    #pragma unroll
    for (int m = 0; m < 5; m++) {
        bf16x8 val = *reinterpret_cast<const bf16x8*>(&lp[m][rl][s * 16 + h * 8]);
        *reinterpret_cast<bf16x8*>(dsts[m] + (size_t)panel * 8192 + (size_t)g * 16) = val;
    }
}

// ---------------- rowsum: fused sim + exp row-sum over 4 jobs ----------------
// job 0: X=G1f vs Y=Af        chunks  0..7
// job 1: X=G2f vs Y=Af        chunks  8..15
// job 2: X=Z1f vs Y={Z1f,Z2f} chunks 16..31
// job 3: X=Z2f vs Y={Z1f,Z2f} chunks 32..47
// SWAPPED OPERANDS (r9): D = mfma(A=Y, B=X) -> reg dim = Y, lane&31 = X-row.
// Y-rowsum happens inside the accumulation loop; both h-halves atomicAdd.
// Per-wave state: xb 32 VGPR + cacc 16 AGPR + 2 scalars (~66 unified) ->
// fits launch_bounds(256,6) cap 85 with margin (WRITE_SIZE = spill tripwire).
// LDS: 32-row Y tiles, 2 x 8 KB double buffer = 16 KB/block.
// Grid (32,48) = 1536 blocks = EXACTLY 6 blocks/CU x 256 CU, single round,
// 24 waves/CU: six independent barrier domains per CU keep the trans pipe
// (v_exp quarter-rate ~20.5 us total = the hard floor) fed while other
// blocks run DS/MFMA/stage phases.
__global__ __launch_bounds__(256, 6) void rowsum_kernel(
    const char* __restrict__ Z1f, const char* __restrict__ Z2f,
    const char* __restrict__ G1f, const char* __restrict__ G2f,
    const char* __restrict__ Af,
    float* __restrict__ S1, float* __restrict__ S2)
{
    int rowblk = blockIdx.x;   // 0..31 : 128 X-rows each
    int chunk  = blockIdx.y;   // 0..47 : 512 Y-rows each

    int job;
    const char *X, *Y;
    int ybase;
    if (chunk < 8)       { job = 0; X = G1f; Y = Af; ybase = chunk * 512; }
    else if (chunk < 16) { job = 1; X = G2f; Y = Af; ybase = (chunk - 8) * 512; }
    else if (chunk < 32) { job = 2; X = Z1f; ybase = (chunk - 16) * 512;
                           Y = (ybase < BN) ? Z1f : Z2f; if (ybase >= BN) ybase -= BN; }
    else                 { job = 3; X = Z2f; ybase = (chunk - 32) * 512;
                           Y = (ybase < BN) ? Z1f : Z2f; if (ybase >= BN) ybase -= BN; }

    __shared__ char lds[2 * 8192];    // double-buffered 32-row Y tiles

    int tid  = threadIdx.x;
    int wid  = tid >> 6;      // 0..3
    int lane = tid & 63;
    int r = lane & 31, h = lane >> 5;
    size_t laneoff = (size_t)(h * 512 + r * 16);

    // B-operand: one 32-row X panel per wave (fragment layout = A layout:
    // lane&31 = row, k = 16s + 8h + j).
    int xrow0 = rowblk * 128 + wid * 32;
    int px = rowblk * 4 + wid;
    const char* xp = X + (size_t)px * 8192 + laneoff;
    bf16x8 xb[8];
    #pragma unroll
    for (int s = 0; s < 8; s++)
        xb[s] = *reinterpret_cast<const bf16x8*>(xp + s * 1024);

    const char* Ychunk = Y + (size_t)ybase * 256;   // 16 panels of 32 rows

    float a0 = 0.f, a1 = 0.f;   // sum e, sum e^2 for X-row xrow0 + r

    // Stage one 32-row panel (8 KB = 512 granules); 2 gload_lds per thread.
    // Dest is wave-uniform base + lane*16 (HW); source adds lane*16 explicitly.
    auto stage = [&](int b, int ct) {
        const char* gsrc = Ychunk + (size_t)ct * 8192;
        #pragma unroll
        for (int i = 0; i < 2; i++)
            gload_lds16(gsrc + (wid * 128 + i * 64 + lane) * 16,
                        lds + b * 8192 + (wid * 128 + i * 64) * 16);
    };

    const char* rbase = lds + laneoff;

    stage(0, 0);
    __syncthreads();
    int cur = 0;
    for (int ct = 0; ct < NTILES; ct++) {
        if (ct + 1 < NTILES) stage(cur ^ 1, ct + 1);   // prefetch next tile
        const char* tb = rbase + cur * 8192;
        f32x16 c;
        #pragma unroll
        for (int q = 0; q < 16; q++) c[q] = 0.f;
        #pragma unroll
        for (int s = 0; s < 8; s++) {
            bf16x8 yfrag = *reinterpret_cast<const bf16x8*>(tb + s * 1024);
            c = __builtin_amdgcn_mfma_f32_32x32x16_bf16(yfrag, xb[s], c, 0, 0, 0);
        }
        // inputs pre-scaled: c = (2*log2 e)*dot -> e = e^(2*dot).
        // Y-rowsum = accumulate the 16 regs (each lane: 16 of 32 Y-rows).
        #pragma unroll
        for (int q = 0; q < 16; q++) {
            float e = fast_exp2(c[q]);
            a0 += e;
            a1 = fmaf(e, e, a1);
        }
        __syncthreads();
        cur ^= 1;
    }

    // Each lane holds partials for X-row xrow0 + r (its h-half of every
    // tile's Y-rows); both h lanes atomicAdd disjoint Y contributions.
    atomicAdd(&S1[job * BN + xrow0 + r], a0);
    atomicAdd(&S2[job * BN + xrow0 + r], a1);
}

// ---------------- finalize: per-row loss terms -> weighted mean --------------
__global__ __launch_bounds__(256) void finalize_kernel(
    const float* __restrict__ S1, const float* __restrict__ S2,
    const float* __restrict__ d1, const float* __restrict__ d2,
    const float* __restrict__ d3, float* __restrict__ out)
{
    int idx = blockIdx.x * 256 + threadIdx.x;   // 0..16383
    float term = 0.f;
    const float EM2 = 0.13533528323661270f;     // e^-2
    if (idx < 8192) {                           // inter jobs 0/1
        int j = idx >> 12, i = idx & 4095;
        float dv = j ? d2[i] : d1[i];
        float n = 4095.f;
        float pos = __expf(2.f * dv);
        float s1 = S1[j * BN + i] - pos;
        float s2 = S2[j * BN + i] - pos * pos;
        float rw = s2 * n / s1;
        float ng = (-0.1f * n * pos + rw) * (1.f / 0.9f);
        ng = fmaxf(ng, n * EM2);
        term = logf((pos + ng) / pos) * (0.5f / 4096.f);
    } else {                                    // intra rows 0..8191
        int i = idx - 8192;
        int ii = i & 4095;
        int job = 2 + (i >> 12);
        float n = 8190.f;
        const float E2 = 7.3890560989306495f, E4 = 54.598150033144236f;
        float pos = __expf(2.f * d3[ii]);
        float s1 = S1[job * BN + ii] - E2 - pos;
        float s2 = S2[job * BN + ii] - E4 - pos * pos;
        float rw = s2 * n / s1;
        float ng = (-0.1f * n * pos + rw) * (1.f / 0.9f);
        ng = fmaxf(ng, n * EM2);
        term = logf((pos + ng) / pos) * (1.f / 8192.f);
    }

    #pragma unroll
    for (int m = 1; m < 64; m <<= 1) term += __shfl_xor(term, m);
    __shared__ float sm[4];
    int wid = threadIdx.x >> 6;
    if ((threadIdx.x & 63) == 0) sm[wid] = term;
    __syncthreads();
    if (threadIdx.x == 0) atomicAdd(out, sm[0] + sm[1] + sm[2] + sm[3]);
}

extern "C" void kernel_launch(void* const* d_in, const int* in_sizes, int n_in,
                              void* d_out, int out_size, void* d_ws, size_t ws_size,
                              hipStream_t stream)
{
    const float* z1   = (const float*)d_in[0];
    const float* z2   = (const float*)d_in[1];
    // d_in[2] = text_z : unused by the reference
    const float* attr = (const float*)d_in[3];
    const int*   uni  = (const int*)d_in[4];
    float* out = (float*)d_out;

    char* ws = (char*)d_ws;
    size_t matb = (size_t)BN * DD * 2;               // bytes per bf16 matrix
    char* Z1f = ws;
    char* Z2f = Z1f + matb;
    char* G1f = Z2f + matb;
    char* G2f = G1f + matb;
    char* Af  = G2f + matb;
    float* S1 = (float*)(ws + 5 * matb);
    float* S2 = S1 + 4 * BN;
    float* d1 = S2 + 4 * BN;
    float* d2 = d1 + BN;
    float* d3 = d2 + BN;

    prep_kernel<<<256, 256, 0, stream>>>(z1, z2, attr, uni,
                                         Z1f, Z2f, G1f, G2f, Af,
                                         d1, d2, d3, S1, S2, out);
    rowsum_kernel<<<dim3(32, 48), 256, 0, stream>>>(Z1f, Z2f, G1f, G2f, Af, S1, S2);
    finalize_kernel<<<64, 256, 0, stream>>>(S1, S2, d1, d2, d3, out);
}